// Round 14
// baseline (175.709 us; speedup 1.0000x reference)
//
#include <hip/hip_runtime.h>
#include <hip/hip_bf16.h>
#include <math.h>

#define DIM 128
#define N_TOT 200
#define FDIM 384
#define NT 16
#define NTILES 13       // 13*16 = 208 >= 200 (tail masked)
#define KSTEPS 12
#define THREADS 256     // 4 waves; wave w owns d-rows [32w, 32w+32)
#define NPAD 256

typedef __attribute__((ext_vector_type(8))) short short8;
typedef __attribute__((ext_vector_type(4))) float f32x4;

__device__ __forceinline__ unsigned pk2(float x, float y) {
    union { __hip_bfloat162 h; unsigned u; } cv;
    cv.h = __float22bfloat162_rn(make_float2(x, y));   // v_cvt_pk_bf16_f32
    return cv.u;
}
__device__ __forceinline__ float fast_tanh(float x) {
    return 1.f - 2.f / (__expf(2.f * x) + 1.f);
}
// 16-lane sum via DPP (VALU pipe, no LDS). Result replicated across the row.
__device__ __forceinline__ float dpp_red16(float x) {
    int v;
    v = __builtin_amdgcn_update_dpp(0, __builtin_bit_cast(int, x), 0xB1, 0xF, 0xF, false);
    x += __builtin_bit_cast(float, v);
    v = __builtin_amdgcn_update_dpp(0, __builtin_bit_cast(int, x), 0x4E, 0xF, 0xF, false);
    x += __builtin_bit_cast(float, v);
    v = __builtin_amdgcn_update_dpp(0, __builtin_bit_cast(int, x), 0x141, 0xF, 0xF, false);
    x += __builtin_bit_cast(float, v);
    v = __builtin_amdgcn_update_dpp(0, __builtin_bit_cast(int, x), 0x140, 0xF, 0xF, false);
    x += __builtin_bit_cast(float, v);
    return x;
}

// ---- pre-kernel: W -> bf16 MFMA B-fragments in d_ws (96 KB, fragment order) ----
// frag(ds,ks,lane) 8 shorts: W[16ds+(lane&15)][32ks+8(lane>>4)+e], e=0..7
__global__ __launch_bounds__(256, 4)
void prep_w(const float* __restrict__ W, unsigned* __restrict__ wsB) {
    int o = blockIdx.x * 256 + threadIdx.x;   // 0..24575 (uint granularity)
    int q = o & 3, lane = (o >> 2) & 63, t = o >> 8;
    int ks = t % 12, ds = t / 12;
    int d = 16 * ds + (lane & 15);
    int f = 32 * ks + 8 * (lane >> 4) + 2 * q;
    wsB[o] = pk2(W[d * FDIM + f], W[d * FDIM + f + 1]);
}

__global__ __launch_bounds__(THREADS, 3)
void acv_kernel(const int* __restrict__ xs_xt,        // [B][N][2]
                const int* __restrict__ path_idx,     // [B][N]
                const float* __restrict__ value_vocab,
                const float* __restrict__ path_vocab,
                const unsigned* __restrict__ wsB,     // W bf16 fragments
                const float* __restrict__ att_vec,
                const float* __restrict__ dense_w,    // [128][128]
                const float* __restrict__ dense_b,
                float* __restrict__ out)              // [B][128]
{
    // ctx tiles in MFMA-fragment granule order, bf16, double-buffered.
    // granule(ks,row,gg): 16B at ks*1024 + ((row*64 + gg*16) ^ ((ks&1)<<6))
    __shared__ __align__(16) char ctx[2][NT * FDIM * 2];   // 2 x 12 KB
    __shared__ float spart[2][4][16];     // [buf][wave][row]
    __shared__ const char* rowp[3 * NPAD];
    __shared__ float code_s[DIM];
    __shared__ float red[2][DIM];

    const int b    = blockIdx.x;
    const int tid  = threadIdx.x;
    const int wave = tid >> 6;        // = d-quarter
    const int lane = tid & 63;
    const int c    = lane & 15;       // MFMA col-within-16
    const int g    = lane >> 4;       // k-slot / row-group

    // ---- per-block: precompute gather row pointers (padded to 256) ----
    const int* xs_b = xs_xt + b * (N_TOT * 2);
    const int* p_b  = path_idx + b * N_TOT;
    for (int i = tid; i < 3 * NPAD; i += THREADS) {
        int seg = i >> 8, n = i & (NPAD - 1);
        int m = n < N_TOT ? n : N_TOT - 1;
        const char* base;
        if      (seg == 0) base = (const char*)(value_vocab + (size_t)xs_b[2 * m]     * DIM);
        else if (seg == 1) base = (const char*)(path_vocab  + (size_t)p_b[m]          * DIM);
        else               base = (const char*)(value_vocab + (size_t)xs_b[2 * m + 1] * DIM);
        rowp[i] = base;
    }
    __syncthreads();

    // ---- staging invariants: 1536 dwordx4 units/tile, 6/thread, coalesced ----
    int ridx[6], ldsb[6];
    const int boff = (tid & 31) * 16;
    #pragma unroll
    for (int p = 0; p < 6; ++p) {
        int u   = tid + THREADS * p;      // 0..1535
        int s   = u >> 5;                 // segment-row 0..47
        int seg = s >> 4, nl = s & 15;
        ridx[p] = seg * NPAD + nl;
        int f  = seg * 128 + (u & 31) * 4;
        int ks = f >> 5, gg = (f >> 3) & 3, hh = (f >> 2) & 1;
        ldsb[p] = ks * 1024 + ((nl * 64 + gg * 16) ^ ((ks & 1) << 6)) + hh * 8;
    }

    auto stage_issue = [&](int t, float4* pf) {
        #pragma unroll
        for (int p = 0; p < 6; ++p) {
            const char* rp = rowp[ridx[p] + t * NT];
            pf[p] = *(const float4*)(rp + boff);
        }
    };
    auto stage_write = [&](char* base, const float4* pf) {
        #pragma unroll
        for (int p = 0; p < 6; ++p) {
            float4 v = pf[p];
            *(uint2*)(base + ldsb[p]) = make_uint2(pk2(v.x, v.y), pk2(v.z, v.w));
        }
    };

    float4 pfA[6], pfB[6];

    // ---- prologue: even-ks W in regs, odd-ks streamed; dual pf sets ----
    stage_issue(0, pfA);
    const char* wb0 = (const char*)wsB + ((2 * wave)     * KSTEPS * 64 + lane) * 16;
    const char* wb1 = (const char*)wsB + ((2 * wave + 1) * KSTEPS * 64 + lane) * 16;
    short8 wfE[12];   // [2j] = ds0 even-ks j, [2j+1] = ds1 even-ks j
    #pragma unroll
    for (int j = 0; j < 6; ++j) {
        wfE[2 * j]     = *(const short8*)(wb0 + (2 * j) * 1024);
        wfE[2 * j + 1] = *(const short8*)(wb1 + (2 * j) * 1024);
    }
    const float a0v = att_vec[32 * wave + c];
    const float a1v = att_vec[32 * wave + 16 + c];

    stage_write(ctx[0], pfA);     // waits pfA (tile 0)
    stage_issue(1, pfB);          // tile 1 in flight (consumed at iter 0)
    stage_issue(2, pfA);          // tile 2 in flight (consumed at iter 1)
    __syncthreads();              // tile 0 visible

    float P0 = 0.f, P1 = 0.f, L = 0.f;
    float comb0[4], comb1[4];
    const int ab = c * 64 + g * 16;

    auto do_tile = [&](int t) {
        const char* cb = ctx[t & 1];
        f32x4 acc0 = {0.f, 0.f, 0.f, 0.f};
        f32x4 acc1 = {0.f, 0.f, 0.f, 0.f};
        #pragma unroll
        for (int j = 0; j < 6; ++j) {
            const int kse = 2 * j, kso = 2 * j + 1;
            // even ks: reg-resident W (sw = 0)
            short8 ae = *(const short8*)(cb + kse * 1024 + ab);
            acc0 = __builtin_amdgcn_mfma_f32_16x16x32_bf16(ae, wfE[2 * j],     acc0, 0, 0, 0);
            acc1 = __builtin_amdgcn_mfma_f32_16x16x32_bf16(ae, wfE[2 * j + 1], acc1, 0, 0, 0);
            // odd ks: W streamed from L2 (sw = 64)
            short8 bo0 = *(const short8*)(wb0 + kso * 1024);
            short8 bo1 = *(const short8*)(wb1 + kso * 1024);
            short8 ao  = *(const short8*)(cb + kso * 1024 + (ab ^ 64));
            acc0 = __builtin_amdgcn_mfma_f32_16x16x32_bf16(ao, bo0, acc0, 0, 0, 0);
            acc1 = __builtin_amdgcn_mfma_f32_16x16x32_bf16(ao, bo1, acc1, 0, 0, 0);
        }
        float sp[4];
        #pragma unroll
        for (int r = 0; r < 4; ++r) {
            comb0[r] = fast_tanh(acc0[r]);
            comb1[r] = fast_tanh(acc1[r]);
            sp[r] = fmaf(comb0[r], a0v, comb1[r] * a1v);
        }
        #pragma unroll
        for (int r = 0; r < 4; ++r) sp[r] = dpp_red16(sp[r]);   // sum over 16 c (VALU)
        if (c == 0) {   // lanes 0,16,32,48: one float4 per row-quad
            *(float4*)&spart[t & 1][wave][4 * g] = make_float4(sp[0], sp[1], sp[2], sp[3]);
        }
    };
    auto finish_tile = [&](int t) {
        f32x4 q0 = *(const f32x4*)&spart[t & 1][0][4 * g];   // broadcast reads
        f32x4 q1 = *(const f32x4*)&spart[t & 1][1][4 * g];
        f32x4 q2 = *(const f32x4*)&spart[t & 1][2][4 * g];
        f32x4 q3 = *(const f32x4*)&spart[t & 1][3][4 * g];
        #pragma unroll
        for (int r = 0; r < 4; ++r) {
            float s = (q0[r] + q1[r]) + (q2[r] + q3[r]);
            float e = (t * NT + 4 * g + r < N_TOT) ? __expf(s) : 0.f;  // |s|<=~5
            L += e;
            P0 = fmaf(e, comb0[r], P0);
            P1 = fmaf(e, comb1[r], P1);
        }
    };

    #pragma unroll 1
    for (int t = 0; t < NTILES; ++t) {
        // invariant: pf[k&1] holds tile k's loads when tile k is written
        if (t + 1 < NTILES) {
            float4* pfw = ((t + 1) & 1) ? pfB : pfA;
            stage_write(ctx[(t + 1) & 1], pfw);
            if (t + 3 < NTILES) stage_issue(t + 3, pfw);
        }
        do_tile(t);
        __syncthreads();   // spart[t&1] ready AND ctx[(t+1)&1] visible
        finish_tile(t);
    }

    // ---- reduce over g (row-quads); code = P/L ----
    P0 += __shfl_xor(P0, 16, 64);
    P0 += __shfl_xor(P0, 32, 64);
    P1 += __shfl_xor(P1, 16, 64);
    P1 += __shfl_xor(P1, 32, 64);
    L  += __shfl_xor(L, 16, 64);
    L  += __shfl_xor(L, 32, 64);
    if (lane < 16) {
        code_s[32 * wave + c]      = P0 / L;
        code_s[32 * wave + 16 + c] = P1 / L;
    }
    __syncthreads();

    // ---- dense + sigmoid ----
    const int o  = tid & 127;
    const int sg = tid >> 7;
    float partial = 0.f;
    #pragma unroll 8
    for (int d = 64 * sg; d < 64 * sg + 64; ++d)
        partial = fmaf(code_s[d], dense_w[d * DIM + o], partial);
    red[sg][o] = partial;
    __syncthreads();
    if (tid < DIM) {
        float a2 = dense_b[tid] + red[0][tid] + red[1][tid];
        out[(size_t)b * DIM + tid] = 1.f / (1.f + __expf(-a2));
    }
}

extern "C" void kernel_launch(void* const* d_in, const int* in_sizes, int n_in,
                              void* d_out, int out_size, void* d_ws, size_t ws_size,
                              hipStream_t stream) {
    const int*   xs_xt       = (const int*)d_in[0];
    const int*   path_idx    = (const int*)d_in[1];
    const float* value_vocab = (const float*)d_in[2];
    const float* path_vocab  = (const float*)d_in[3];
    const float* W           = (const float*)d_in[4];
    const float* att_vec     = (const float*)d_in[5];
    const float* dense_w     = (const float*)d_in[6];
    const float* dense_b     = (const float*)d_in[7];
    float*       out         = (float*)d_out;

    unsigned* wsB = (unsigned*)d_ws;    // 24576 uints = 96 KB

    prep_w<<<96, 256, 0, stream>>>(W, wsB);
    acv_kernel<<<1024, THREADS, 0, stream>>>(xs_xt, path_idx, value_vocab, path_vocab,
                                             wsB, att_vec, dense_w, dense_b, out);
}

// Round 15
// 154.797 us; speedup vs baseline: 1.1351x; 1.1351x over previous
//
#include <hip/hip_runtime.h>
#include <hip/hip_bf16.h>
#include <math.h>

#define DIM 128
#define N_TOT 200
#define FDIM 384
#define NT 16
#define NTILES 13       // 13*16 = 208 >= 200 (tail masked)
#define KSTEPS 12
#define THREADS 256     // 4 waves; wave w owns d-rows [32w, 32w+32)
#define NPAD 256
#define NTASKS 1024
#define GRID_P 768      // 3 blocks/CU x 256 CUs

typedef __attribute__((ext_vector_type(8))) short short8;
typedef __attribute__((ext_vector_type(4))) float f32x4;

__device__ __forceinline__ unsigned pk2(float x, float y) {
    union { __hip_bfloat162 h; unsigned u; } cv;
    cv.h = __float22bfloat162_rn(make_float2(x, y));   // v_cvt_pk_bf16_f32
    return cv.u;
}
__device__ __forceinline__ float fast_tanh(float x) {
    return 1.f - 2.f / (__expf(2.f * x) + 1.f);
}
// 16-lane sum via DPP (VALU pipe, no LDS). Result replicated across the row.
__device__ __forceinline__ float dpp_red16(float x) {
    int v;
    v = __builtin_amdgcn_update_dpp(0, __builtin_bit_cast(int, x), 0xB1, 0xF, 0xF, false);
    x += __builtin_bit_cast(float, v);
    v = __builtin_amdgcn_update_dpp(0, __builtin_bit_cast(int, x), 0x4E, 0xF, 0xF, false);
    x += __builtin_bit_cast(float, v);
    v = __builtin_amdgcn_update_dpp(0, __builtin_bit_cast(int, x), 0x141, 0xF, 0xF, false);
    x += __builtin_bit_cast(float, v);
    v = __builtin_amdgcn_update_dpp(0, __builtin_bit_cast(int, x), 0x140, 0xF, 0xF, false);
    x += __builtin_bit_cast(float, v);
    return x;
}

// ---- pre-kernel: W -> bf16 MFMA B-fragments in d_ws (96 KB) + counter reset ----
// frag(ds,ks,lane) 8 shorts: W[16ds+(lane&15)][32ks+8(lane>>4)+e], e=0..7
__global__ __launch_bounds__(256, 4)
void prep_w(const float* __restrict__ W, unsigned* __restrict__ wsB,
            unsigned* __restrict__ cnt) {
    if (blockIdx.x == 0 && threadIdx.x == 0) *cnt = 0u;   // work-queue reset (every launch)
    int o = blockIdx.x * 256 + threadIdx.x;   // 0..24575 (uint granularity)
    int q = o & 3, lane = (o >> 2) & 63, t = o >> 8;
    int ks = t % 12, ds = t / 12;
    int d = 16 * ds + (lane & 15);
    int f = 32 * ks + 8 * (lane >> 4) + 2 * q;
    wsB[o] = pk2(W[d * FDIM + f], W[d * FDIM + f + 1]);
}

__global__ __launch_bounds__(THREADS, 3)
void acv_kernel(const int* __restrict__ xs_xt,        // [B][N][2]
                const int* __restrict__ path_idx,     // [B][N]
                const float* __restrict__ value_vocab,
                const float* __restrict__ path_vocab,
                const unsigned* __restrict__ wsB,     // W bf16 fragments
                unsigned* __restrict__ cnt,           // work queue
                const float* __restrict__ att_vec,
                const float* __restrict__ dense_w,    // [128][128]
                const float* __restrict__ dense_b,
                float* __restrict__ out)              // [B][128]
{
    // ctx tiles in MFMA-fragment granule order, bf16, double-buffered.
    // granule(ks,row,gg): 16B at ks*1024 + ((row*64 + gg*16) ^ ((ks&1)<<6))
    __shared__ __align__(16) char ctx[2][NT * FDIM * 2];   // 2 x 12 KB
    __shared__ float spart[2][4][16];     // [buf][wave][row]
    __shared__ const char* rowp[3 * NPAD];
    __shared__ float code_s[DIM];
    __shared__ float red[2][DIM];
    __shared__ unsigned task_s;

    const int tid  = threadIdx.x;
    const int wave = tid >> 6;        // = d-quarter
    const int lane = tid & 63;
    const int c    = lane & 15;       // MFMA col-within-16
    const int g    = lane >> 4;       // k-slot / row-group

    // ---- task-invariant setup (once per persistent block) ----
    int ridx[6], ldsb[6];
    const int boff = (tid & 31) * 16;
    #pragma unroll
    for (int p = 0; p < 6; ++p) {
        int u   = tid + THREADS * p;      // 0..1535
        int s   = u >> 5;                 // segment-row 0..47
        int seg = s >> 4, nl = s & 15;
        ridx[p] = seg * NPAD + nl;
        int f  = seg * 128 + (u & 31) * 4;
        int ks = f >> 5, gg = (f >> 3) & 3, hh = (f >> 2) & 1;
        ldsb[p] = ks * 1024 + ((nl * 64 + gg * 16) ^ ((ks & 1) << 6)) + hh * 8;
    }
    // W slice (32 d per wave) fully register-resident, loaded once
    short8 wf0[KSTEPS], wf1[KSTEPS];
    {
        const char* wb = (const char*)wsB;
        const int ds0 = 2 * wave, ds1 = 2 * wave + 1;
        #pragma unroll
        for (int ks = 0; ks < KSTEPS; ++ks) {
            wf0[ks] = *(const short8*)(wb + ((ds0 * KSTEPS + ks) * 64 + lane) * 16);
            wf1[ks] = *(const short8*)(wb + ((ds1 * KSTEPS + ks) * 64 + lane) * 16);
        }
    }
    const float a0v = att_vec[32 * wave + c];
    const float a1v = att_vec[32 * wave + 16 + c];
    const int ab = c * 64 + g * 16;

    auto stage_issue = [&](int t, float4* pf) {
        #pragma unroll
        for (int p = 0; p < 6; ++p) {
            const char* rp = rowp[ridx[p] + t * NT];
            pf[p] = *(const float4*)(rp + boff);
        }
    };
    auto stage_write = [&](char* base, const float4* pf) {
        #pragma unroll
        for (int p = 0; p < 6; ++p) {
            float4 v = pf[p];
            *(uint2*)(base + ldsb[p]) = make_uint2(pk2(v.x, v.y), pk2(v.z, v.w));
        }
    };

    float4 pfA[6];
    float P0, P1, L;
    float comb0[4], comb1[4];

    auto do_tile = [&](int t) {
        const char* cb = ctx[t & 1];
        f32x4 acc0 = {0.f, 0.f, 0.f, 0.f};
        f32x4 acc1 = {0.f, 0.f, 0.f, 0.f};
        #pragma unroll
        for (int ks = 0; ks < KSTEPS; ++ks) {
            short8 a = *(const short8*)(cb + ks * 1024 + (ab ^ ((ks & 1) << 6)));
            acc0 = __builtin_amdgcn_mfma_f32_16x16x32_bf16(a, wf0[ks], acc0, 0, 0, 0);
            acc1 = __builtin_amdgcn_mfma_f32_16x16x32_bf16(a, wf1[ks], acc1, 0, 0, 0);
        }
        float sp[4];
        #pragma unroll
        for (int r = 0; r < 4; ++r) {
            comb0[r] = fast_tanh(acc0[r]);
            comb1[r] = fast_tanh(acc1[r]);
            sp[r] = fmaf(comb0[r], a0v, comb1[r] * a1v);
        }
        #pragma unroll
        for (int r = 0; r < 4; ++r) sp[r] = dpp_red16(sp[r]);   // sum over 16 c (VALU)
        if (c == 0) {   // lanes 0,16,32,48: one float4 per row-quad
            *(float4*)&spart[t & 1][wave][4 * g] = make_float4(sp[0], sp[1], sp[2], sp[3]);
        }
    };
    auto finish_tile = [&](int t) {
        f32x4 q0 = *(const f32x4*)&spart[t & 1][0][4 * g];   // broadcast reads
        f32x4 q1 = *(const f32x4*)&spart[t & 1][1][4 * g];
        f32x4 q2 = *(const f32x4*)&spart[t & 1][2][4 * g];
        f32x4 q3 = *(const f32x4*)&spart[t & 1][3][4 * g];
        #pragma unroll
        for (int r = 0; r < 4; ++r) {
            float s = (q0[r] + q1[r]) + (q2[r] + q3[r]);
            float e = (t * NT + 4 * g + r < N_TOT) ? __expf(s) : 0.f;  // |s|<=~5
            L += e;
            P0 = fmaf(e, comb0[r], P0);
            P1 = fmaf(e, comb1[r], P1);
        }
    };

    // ---- persistent task loop ----
    for (;;) {
        if (tid == 0) task_s = atomicAdd(cnt, 1u);
        __syncthreads();                    // publish task; fence previous task's LDS reads
        const unsigned b = task_s;
        if (b >= NTASKS) break;

        // per-task: gather row pointers (padded to 256)
        const int* xs_b = xs_xt + b * (N_TOT * 2);
        const int* p_b  = path_idx + b * N_TOT;
        for (int i = tid; i < 3 * NPAD; i += THREADS) {
            int seg = i >> 8, n = i & (NPAD - 1);
            int m = n < N_TOT ? n : N_TOT - 1;
            const char* base;
            if      (seg == 0) base = (const char*)(value_vocab + (size_t)xs_b[2 * m]     * DIM);
            else if (seg == 1) base = (const char*)(path_vocab  + (size_t)p_b[m]          * DIM);
            else               base = (const char*)(value_vocab + (size_t)xs_b[2 * m + 1] * DIM);
            rowp[i] = base;
        }
        __syncthreads();

        stage_issue(0, pfA);
        stage_write(ctx[0], pfA);     // waits pfA (tile 0)
        stage_issue(1, pfA);          // tile 1 in flight
        __syncthreads();              // tile 0 visible

        P0 = 0.f; P1 = 0.f; L = 0.f;

        #pragma unroll 1
        for (int t = 0; t < NTILES; ++t) {
            if (t + 1 < NTILES) {
                stage_write(ctx[(t + 1) & 1], pfA);     // tile t+1 (issued at t-1)
                if (t + 2 < NTILES) stage_issue(t + 2, pfA);
            }
            do_tile(t);
            __syncthreads();   // spart[t&1] ready AND ctx[(t+1)&1] visible
            finish_tile(t);
        }

        // reduce over g (row-quads); code = P/L
        P0 += __shfl_xor(P0, 16, 64);
        P0 += __shfl_xor(P0, 32, 64);
        P1 += __shfl_xor(P1, 16, 64);
        P1 += __shfl_xor(P1, 32, 64);
        L  += __shfl_xor(L, 16, 64);
        L  += __shfl_xor(L, 32, 64);
        if (lane < 16) {
            code_s[32 * wave + c]      = P0 / L;
            code_s[32 * wave + 16 + c] = P1 / L;
        }
        __syncthreads();

        // dense + sigmoid
        const int o  = tid & 127;
        const int sg = tid >> 7;
        float partial = 0.f;
        #pragma unroll 8
        for (int d = 64 * sg; d < 64 * sg + 64; ++d)
            partial = fmaf(code_s[d], dense_w[d * DIM + o], partial);
        red[sg][o] = partial;
        __syncthreads();
        if (tid < DIM) {
            float a2 = dense_b[tid] + red[0][tid] + red[1][tid];
            out[(size_t)b * DIM + tid] = 1.f / (1.f + __expf(-a2));
        }
    }
}

extern "C" void kernel_launch(void* const* d_in, const int* in_sizes, int n_in,
                              void* d_out, int out_size, void* d_ws, size_t ws_size,
                              hipStream_t stream) {
    const int*   xs_xt       = (const int*)d_in[0];
    const int*   path_idx    = (const int*)d_in[1];
    const float* value_vocab = (const float*)d_in[2];
    const float* path_vocab  = (const float*)d_in[3];
    const float* W           = (const float*)d_in[4];
    const float* att_vec     = (const float*)d_in[5];
    const float* dense_w     = (const float*)d_in[6];
    const float* dense_b     = (const float*)d_in[7];
    float*       out         = (float*)d_out;

    unsigned* wsB = (unsigned*)d_ws;    // 24576 uints = 96 KB
    unsigned* cnt = wsB + 24576;        // work-queue counter

    prep_w<<<96, 256, 0, stream>>>(W, wsB, cnt);
    acv_kernel<<<GRID_P, THREADS, 0, stream>>>(xs_xt, path_idx, value_vocab, path_vocab,
                                               wsB, cnt, att_vec, dense_w, dense_b, out);
}

// Round 16
// 70.599 us; speedup vs baseline: 2.4888x; 2.1926x over previous
//
#include <hip/hip_runtime.h>
#include <hip/hip_bf16.h>
#include <math.h>

#define DIM 128
#define N_TOT 200
#define FDIM 384
#define NT 16
#define NTILES 13       // 13*16 = 208 >= 200 (tail masked)
#define KSTEPS 12
#define THREADS 256     // 4 waves; wave w owns d-rows [32w, 32w+32)
#define NPAD 256

typedef __attribute__((ext_vector_type(8))) short short8;
typedef __attribute__((ext_vector_type(4))) float f32x4;

__device__ __forceinline__ unsigned pk2(float x, float y) {
    union { __hip_bfloat162 h; unsigned u; } cv;
    cv.h = __float22bfloat162_rn(make_float2(x, y));   // v_cvt_pk_bf16_f32
    return cv.u;
}
__device__ __forceinline__ float fast_tanh(float x) {
    return 1.f - 2.f / (__expf(2.f * x) + 1.f);
}
// 16-lane sum via DPP (VALU pipe, no LDS). Result replicated across the row.
__device__ __forceinline__ float dpp_red16(float x) {
    int v;
    v = __builtin_amdgcn_update_dpp(0, __builtin_bit_cast(int, x), 0xB1, 0xF, 0xF, false);
    x += __builtin_bit_cast(float, v);
    v = __builtin_amdgcn_update_dpp(0, __builtin_bit_cast(int, x), 0x4E, 0xF, 0xF, false);
    x += __builtin_bit_cast(float, v);
    v = __builtin_amdgcn_update_dpp(0, __builtin_bit_cast(int, x), 0x141, 0xF, 0xF, false);
    x += __builtin_bit_cast(float, v);
    v = __builtin_amdgcn_update_dpp(0, __builtin_bit_cast(int, x), 0x140, 0xF, 0xF, false);
    x += __builtin_bit_cast(float, v);
    return x;
}

// ---- pre-kernel: W -> bf16 MFMA B-fragments in d_ws (96 KB, fragment order) ----
// frag(ds,ks,lane) 8 shorts: W[16ds+(lane&15)][32ks+8(lane>>4)+e], e=0..7
__global__ __launch_bounds__(256, 4)
void prep_w(const float* __restrict__ W, unsigned* __restrict__ wsB) {
    int o = blockIdx.x * 256 + threadIdx.x;   // 0..24575 (uint granularity)
    int q = o & 3, lane = (o >> 2) & 63, t = o >> 8;
    int ks = t % 12, ds = t / 12;
    int d = 16 * ds + (lane & 15);
    int f = 32 * ks + 8 * (lane >> 4) + 2 * q;
    wsB[o] = pk2(W[d * FDIM + f], W[d * FDIM + f + 1]);
}

__global__ __launch_bounds__(THREADS, 3)
void acv_kernel(const int* __restrict__ xs_xt,        // [B][N][2]
                const int* __restrict__ path_idx,     // [B][N]
                const float* __restrict__ value_vocab,
                const float* __restrict__ path_vocab,
                const unsigned* __restrict__ wsB,     // W bf16 fragments
                const float* __restrict__ att_vec,
                const float* __restrict__ dense_w,    // [128][128]
                const float* __restrict__ dense_b,
                float* __restrict__ out)              // [B][128]
{
    // ctx tiles in MFMA-fragment granule order, bf16, double-buffered.
    // granule(ks,row,gg): 16B at ks*1024 + ((row*64 + gg*16) ^ ((ks&1)<<6))
    __shared__ __align__(16) char ctx[2][NT * FDIM * 2];   // 2 x 12 KB
    __shared__ float spart[2][4][16];     // [buf][wave][row]
    __shared__ const char* rowp[3 * NPAD];
    __shared__ float code_s[DIM];
    __shared__ float red[2][DIM];

    const int b    = blockIdx.x;
    const int tid  = threadIdx.x;
    const int wave = tid >> 6;        // = d-quarter
    const int lane = tid & 63;
    const int c    = lane & 15;       // MFMA col-within-16
    const int g    = lane >> 4;       // k-slot / row-group

    // ---- per-block: precompute gather row pointers (padded to 256) ----
    const int* xs_b = xs_xt + b * (N_TOT * 2);
    const int* p_b  = path_idx + b * N_TOT;
    for (int i = tid; i < 3 * NPAD; i += THREADS) {
        int seg = i >> 8, n = i & (NPAD - 1);
        int m = n < N_TOT ? n : N_TOT - 1;
        const char* base;
        if      (seg == 0) base = (const char*)(value_vocab + (size_t)xs_b[2 * m]     * DIM);
        else if (seg == 1) base = (const char*)(path_vocab  + (size_t)p_b[m]          * DIM);
        else               base = (const char*)(value_vocab + (size_t)xs_b[2 * m + 1] * DIM);
        rowp[i] = base;
    }
    __syncthreads();

    // ---- staging invariants: 1536 dwordx4 units/tile, 6/thread, coalesced ----
    int ridx[6], ldsb[6];
    const int boff = (tid & 31) * 16;
    #pragma unroll
    for (int p = 0; p < 6; ++p) {
        int u   = tid + THREADS * p;      // 0..1535
        int s   = u >> 5;                 // segment-row 0..47
        int seg = s >> 4, nl = s & 15;
        ridx[p] = seg * NPAD + nl;
        int f  = seg * 128 + (u & 31) * 4;
        int ks = f >> 5, gg = (f >> 3) & 3, hh = (f >> 2) & 1;
        ldsb[p] = ks * 1024 + ((nl * 64 + gg * 16) ^ ((ks & 1) << 6)) + hh * 8;
    }

    auto stage_issue = [&](int t, float4* pf) {
        #pragma unroll
        for (int p = 0; p < 6; ++p) {
            const char* rp = rowp[ridx[p] + t * NT];
            pf[p] = *(const float4*)(rp + boff);
        }
    };
    auto stage_write = [&](char* base, const float4* pf) {
        #pragma unroll
        for (int p = 0; p < 6; ++p) {
            float4 v = pf[p];
            *(uint2*)(base + ldsb[p]) = make_uint2(pk2(v.x, v.y), pk2(v.z, v.w));
        }
    };

    float4 pfA[6];

    // ---- prologue: W slice (32 d) fully register-resident ----
    stage_issue(0, pfA);
    short8 wf0[KSTEPS], wf1[KSTEPS];
    {
        const char* wb = (const char*)wsB;
        const int ds0 = 2 * wave, ds1 = 2 * wave + 1;
        #pragma unroll
        for (int ks = 0; ks < KSTEPS; ++ks) {
            wf0[ks] = *(const short8*)(wb + ((ds0 * KSTEPS + ks) * 64 + lane) * 16);
            wf1[ks] = *(const short8*)(wb + ((ds1 * KSTEPS + ks) * 64 + lane) * 16);
        }
    }
    const float a0v = att_vec[32 * wave + c];
    const float a1v = att_vec[32 * wave + 16 + c];

    stage_write(ctx[0], pfA);     // waits pfA (tile 0)
    stage_issue(1, pfA);          // tile 1 in flight
    __syncthreads();              // tile 0 visible

    float P0 = 0.f, P1 = 0.f, L = 0.f;
    float comb0[4], comb1[4];
    const int ab = c * 64 + g * 16;

    auto do_tile = [&](int t) {
        const char* cb = ctx[t & 1];
        f32x4 acc0 = {0.f, 0.f, 0.f, 0.f};
        f32x4 acc1 = {0.f, 0.f, 0.f, 0.f};
        #pragma unroll
        for (int ks = 0; ks < KSTEPS; ++ks) {
            short8 a = *(const short8*)(cb + ks * 1024 + (ab ^ ((ks & 1) << 6)));
            acc0 = __builtin_amdgcn_mfma_f32_16x16x32_bf16(a, wf0[ks], acc0, 0, 0, 0);
            acc1 = __builtin_amdgcn_mfma_f32_16x16x32_bf16(a, wf1[ks], acc1, 0, 0, 0);
        }
        float sp[4];
        #pragma unroll
        for (int r = 0; r < 4; ++r) {
            comb0[r] = fast_tanh(acc0[r]);
            comb1[r] = fast_tanh(acc1[r]);
            sp[r] = fmaf(comb0[r], a0v, comb1[r] * a1v);
        }
        #pragma unroll
        for (int r = 0; r < 4; ++r) sp[r] = dpp_red16(sp[r]);   // sum over 16 c (VALU)
        if (c == 0) {   // lanes 0,16,32,48: one float4 per row-quad
            *(float4*)&spart[t & 1][wave][4 * g] = make_float4(sp[0], sp[1], sp[2], sp[3]);
        }
    };
    auto finish_tile = [&](int t) {
        f32x4 q0 = *(const f32x4*)&spart[t & 1][0][4 * g];   // broadcast reads
        f32x4 q1 = *(const f32x4*)&spart[t & 1][1][4 * g];
        f32x4 q2 = *(const f32x4*)&spart[t & 1][2][4 * g];
        f32x4 q3 = *(const f32x4*)&spart[t & 1][3][4 * g];
        #pragma unroll
        for (int r = 0; r < 4; ++r) {
            float s = (q0[r] + q1[r]) + (q2[r] + q3[r]);
            float e = (t * NT + 4 * g + r < N_TOT) ? __expf(s) : 0.f;  // |s|<=~5
            L += e;
            P0 = fmaf(e, comb0[r], P0);
            P1 = fmaf(e, comb1[r], P1);
        }
    };

    #pragma unroll 1
    for (int t = 0; t < NTILES; ++t) {
        if (t + 1 < NTILES) {
            stage_write(ctx[(t + 1) & 1], pfA);     // tile t+1 (issued at t-1)
            if (t + 2 < NTILES) stage_issue(t + 2, pfA);
        }
        do_tile(t);
        __syncthreads();   // spart[t&1] ready AND ctx[(t+1)&1] visible
        finish_tile(t);
    }

    // ---- reduce over g (row-quads); code = P/L ----
    P0 += __shfl_xor(P0, 16, 64);
    P0 += __shfl_xor(P0, 32, 64);
    P1 += __shfl_xor(P1, 16, 64);
    P1 += __shfl_xor(P1, 32, 64);
    L  += __shfl_xor(L, 16, 64);
    L  += __shfl_xor(L, 32, 64);
    if (lane < 16) {
        code_s[32 * wave + c]      = P0 / L;
        code_s[32 * wave + 16 + c] = P1 / L;
    }
    __syncthreads();

    // ---- dense + sigmoid ----
    const int o  = tid & 127;
    const int sg = tid >> 7;
    float partial = 0.f;
    #pragma unroll 8
    for (int d = 64 * sg; d < 64 * sg + 64; ++d)
        partial = fmaf(code_s[d], dense_w[d * DIM + o], partial);
    red[sg][o] = partial;
    __syncthreads();
    if (tid < DIM) {
        float a2 = dense_b[tid] + red[0][tid] + red[1][tid];
        out[(size_t)b * DIM + tid] = 1.f / (1.f + __expf(-a2));
    }
}

extern "C" void kernel_launch(void* const* d_in, const int* in_sizes, int n_in,
                              void* d_out, int out_size, void* d_ws, size_t ws_size,
                              hipStream_t stream) {
    const int*   xs_xt       = (const int*)d_in[0];
    const int*   path_idx    = (const int*)d_in[1];
    const float* value_vocab = (const float*)d_in[2];
    const float* path_vocab  = (const float*)d_in[3];
    const float* W           = (const float*)d_in[4];
    const float* att_vec     = (const float*)d_in[5];
    const float* dense_w     = (const float*)d_in[6];
    const float* dense_b     = (const float*)d_in[7];
    float*       out         = (float*)d_out;

    unsigned* wsB = (unsigned*)d_ws;    // 24576 uints = 96 KB

    prep_w<<<96, 256, 0, stream>>>(W, wsB);
    acv_kernel<<<1024, THREADS, 0, stream>>>(xs_xt, path_idx, value_vocab, path_vocab,
                                             wsB, att_vec, dense_w, dense_b, out);
}